// Round 1
// baseline (261.162 us; speedup 1.0000x reference)
//
#include <hip/hip_runtime.h>
#include <hip/hip_bf16.h>
#include <math.h>

typedef __bf16 bf16x8 __attribute__((ext_vector_type(8)));
typedef float f32x4 __attribute__((ext_vector_type(4)));

#define DIM 128

// ---------------------------------------------------------------------------
// Kernel 1: transpose + bf16-convert the three 128x128 weight matrices.
// Wt[which][n][k] = (bf16) W[k][n]  -> MFMA B-fragment reads become 16B loads.
// grid (64, 3), block 256  (64*256 = 16384 = 128*128)
// ---------------------------------------------------------------------------
__global__ __launch_bounds__(256) void prep_w_kernel(
    const float* __restrict__ Wq, const float* __restrict__ Wk,
    const float* __restrict__ Wv, __bf16* __restrict__ Wt)
{
    const float* W = (blockIdx.y == 0) ? Wq : (blockIdx.y == 1) ? Wk : Wv;
    __bf16* dst = Wt + (size_t)blockIdx.y * DIM * DIM;
    int idx = blockIdx.x * 256 + threadIdx.x;   // coalesced read
    int k = idx >> 7;
    int n = idx & 127;
    dst[n * DIM + k] = (__bf16)W[idx];
}

// ---------------------------------------------------------------------------
// Kernel 2: CSR row_ptr from sorted rows[] via per-row lower_bound.
// ---------------------------------------------------------------------------
__global__ __launch_bounds__(256) void row_ptr_kernel(
    const int* __restrict__ rows, int* __restrict__ row_ptr, int n, int e)
{
    int r = blockIdx.x * 256 + threadIdx.x;
    if (r > n) return;
    if (r == n) { row_ptr[n] = e; return; }
    int lo = 0, hi = e;
    while (lo < hi) {
        int mid = (lo + hi) >> 1;
        if (rows[mid] < r) lo = mid + 1; else hi = mid;
    }
    row_ptr[r] = lo;
}

// ---------------------------------------------------------------------------
// Kernel 3: fused projection GEMM  Y = gelu(X @ W + b), output bf16.
// blockIdx.y selects (q|k|v). Block = 256 thr = 4 waves; block tile 128 rows.
// Wave tile: 32 rows x 128 cols = 2 row-tiles x 8 col-tiles of 16x16 MFMA,
// K = 128 = 4 k-steps of mfma_f32_16x16x32_bf16.
// A frags from global fp32 (each element read exactly once device-wide),
// B frags from pre-transposed bf16 Wt (L1/L2 resident, 32KB).
// A layout: A[m=lane&15][k=quad*8+j]; C/D: col=lane&15, row=quad*4+reg.
// ---------------------------------------------------------------------------
__global__ __launch_bounds__(256) void proj_gemm_kernel(
    const float* __restrict__ query, const float* __restrict__ memory,
    const __bf16* __restrict__ Wt,
    const float* __restrict__ bq, const float* __restrict__ bk,
    const float* __restrict__ bv,
    __bf16* __restrict__ qout, __bf16* __restrict__ kout,
    __bf16* __restrict__ vout, int n, int m)
{
    int which = blockIdx.y;
    const float* X    = (which == 0) ? query : memory;
    const __bf16* Wm  = Wt + (size_t)which * DIM * DIM;
    const float* bias = (which == 0) ? bq : (which == 1) ? bk : bv;
    __bf16* Y         = (which == 0) ? qout : (which == 1) ? kout : vout;
    int R             = (which == 0) ? n : m;

    int wave = threadIdx.x >> 6;
    int lane = threadIdx.x & 63;
    int quad = lane >> 4;
    int l16  = lane & 15;
    int row_base = blockIdx.x * 128 + wave * 32;
    if (row_base >= R) return;

    // Load + convert A fragments for both 16-row tiles, all 4 k-steps.
    bf16x8 afrag[2][4];
    for (int rt = 0; rt < 2; ++rt) {
        int row = row_base + rt * 16 + l16;
        if (row >= R) row = R - 1;                 // clamp (stores predicated)
        const float* xp = X + (size_t)row * DIM + quad * 8;
        for (int ks = 0; ks < 4; ++ks) {
            float4 x0 = *(const float4*)(xp + ks * 32);
            float4 x1 = *(const float4*)(xp + ks * 32 + 4);
            bf16x8 a;
            a[0] = (__bf16)x0.x; a[1] = (__bf16)x0.y;
            a[2] = (__bf16)x0.z; a[3] = (__bf16)x0.w;
            a[4] = (__bf16)x1.x; a[5] = (__bf16)x1.y;
            a[6] = (__bf16)x1.z; a[7] = (__bf16)x1.w;
            afrag[rt][ks] = a;
        }
    }

    for (int ct = 0; ct < 8; ++ct) {
        const __bf16* wp = Wm + (size_t)(ct * 16 + l16) * DIM + quad * 8;
        f32x4 acc0 = {0.f, 0.f, 0.f, 0.f};
        f32x4 acc1 = {0.f, 0.f, 0.f, 0.f};
        for (int ks = 0; ks < 4; ++ks) {
            bf16x8 b = *(const bf16x8*)(wp + ks * 32);
            acc0 = __builtin_amdgcn_mfma_f32_16x16x32_bf16(afrag[0][ks], b, acc0, 0, 0, 0);
            acc1 = __builtin_amdgcn_mfma_f32_16x16x32_bf16(afrag[1][ks], b, acc1, 0, 0, 0);
        }
        float bval = bias[ct * 16 + l16];
        for (int rt = 0; rt < 2; ++rt) {
            f32x4 acc = rt ? acc1 : acc0;
            for (int reg = 0; reg < 4; ++reg) {
                int row = row_base + rt * 16 + quad * 4 + reg;
                if (row < R) {
                    float x = acc[reg] + bval;
                    // jax.nn.gelu approximate=True (tanh form)
                    float t  = 0.7978845608028654f * (x + 0.044715f * x * x * x);
                    float th = 1.0f - 2.0f / (__expf(2.0f * t) + 1.0f);
                    float g  = 0.5f * x * (1.0f + th);
                    Y[(size_t)row * DIM + ct * 16 + l16] = (__bf16)g;
                }
            }
        }
    }
}

// ---------------------------------------------------------------------------
// Kernel 4: per-row edge attention, one wave per row, online softmax.
// 4 edges processed per group: quarter = lane>>4 picks the edge,
// l16 = lane&15 picks 8 dims. k/v gathers = contiguous 256B per edge.
// Per-quarter (m,s,acc) online-softmax state; merged via shfl_xor(16/32).
// ---------------------------------------------------------------------------
__global__ __launch_bounds__(256) void edge_attn_kernel(
    const __bf16* __restrict__ qmat, const __bf16* __restrict__ kmat,
    const __bf16* __restrict__ vmat, const float* __restrict__ adj_vals,
    const int* __restrict__ cols, const int* __restrict__ row_ptr,
    float* __restrict__ out, int n)
{
    int row = blockIdx.x * 4 + (threadIdx.x >> 6);
    if (row >= n) return;
    int lane    = threadIdx.x & 63;
    int quarter = lane >> 4;
    int l16     = lane & 15;

    int start = row_ptr[row];
    int end   = row_ptr[row + 1];

    float qv[8];
    {
        bf16x8 qb = *(const bf16x8*)(qmat + (size_t)row * DIM + l16 * 8);
        for (int j = 0; j < 8; ++j) qv[j] = (float)qb[j];
    }

    float m_q = -1e30f, s_q = 0.0f;
    float acc[8];
    for (int j = 0; j < 8; ++j) acc[j] = 0.0f;

    const float inv_sqrt_d = 0.08838834764831845f;  // 1/sqrt(128)

    int ng = (end - start + 3) >> 2;
    for (int g = 0; g < ng; ++g) {
        int e = start + g * 4 + quarter;
        bool valid = (e < end);
        int   col = valid ? cols[e]     : 0;
        float adj = valid ? adj_vals[e] : 0.0f;
        bf16x8 kb = *(const bf16x8*)(kmat + (size_t)col * DIM + l16 * 8);
        bf16x8 vb = *(const bf16x8*)(vmat + (size_t)col * DIM + l16 * 8);
        float partial = 0.0f;
        for (int j = 0; j < 8; ++j) partial += qv[j] * (float)kb[j];
        partial += __shfl_xor(partial, 1);
        partial += __shfl_xor(partial, 2);
        partial += __shfl_xor(partial, 4);
        partial += __shfl_xor(partial, 8);
        float score = valid ? partial * adj * inv_sqrt_d : -1e30f;
        float m_new = fmaxf(m_q, score);
        float f = __expf(m_q - m_new);            // -1e30 arg -> 0, no NaN
        float p = valid ? __expf(score - m_new) : 0.0f;
        s_q = s_q * f + p;
        m_q = m_new;
        for (int j = 0; j < 8; ++j) acc[j] = acc[j] * f + p * (float)vb[j];
    }

    // Merge the 4 per-quarter online-softmax states.
    float m_all = m_q;
    m_all = fmaxf(m_all, __shfl_xor(m_all, 16));
    m_all = fmaxf(m_all, __shfl_xor(m_all, 32));
    float f = __expf(m_q - m_all);
    float s_sc = s_q * f;
    s_sc += __shfl_xor(s_sc, 16);
    s_sc += __shfl_xor(s_sc, 32);
    float inv = (s_sc > 0.0f) ? 1.0f / s_sc : 0.0f;  // empty row -> zeros

    float o[8];
    for (int j = 0; j < 8; ++j) {
        float a = acc[j] * f;
        a += __shfl_xor(a, 16);
        a += __shfl_xor(a, 32);
        o[j] = a * inv;
    }
    if (quarter == 0) {
        float4* dst = (float4*)(out + (size_t)row * DIM + l16 * 8);
        dst[0] = make_float4(o[0], o[1], o[2], o[3]);
        dst[1] = make_float4(o[4], o[5], o[6], o[7]);
    }
}

// ---------------------------------------------------------------------------
extern "C" void kernel_launch(void* const* d_in, const int* in_sizes, int n_in,
                              void* d_out, int out_size, void* d_ws, size_t ws_size,
                              hipStream_t stream)
{
    const float* query    = (const float*)d_in[0];
    const float* memory   = (const float*)d_in[1];
    const float* adj_vals = (const float*)d_in[2];
    const float* Wq       = (const float*)d_in[3];
    const float* bq       = (const float*)d_in[4];
    const float* Wk       = (const float*)d_in[5];
    const float* bk       = (const float*)d_in[6];
    const float* Wv       = (const float*)d_in[7];
    const float* bv       = (const float*)d_in[8];
    const int*   rows     = (const int*)d_in[9];
    const int*   cols     = (const int*)d_in[10];
    float* out = (float*)d_out;

    int n = in_sizes[0] / DIM;   // 50000
    int m = in_sizes[1] / DIM;   // 50000
    int e = in_sizes[9];         // 1600000

    // Workspace layout (all 16B-aligned):
    char* ws = (char*)d_ws;
    size_t off = 0;
    __bf16* Wt = (__bf16*)(ws + off); off += (size_t)3 * DIM * DIM * 2;  // 98304
    __bf16* qb = (__bf16*)(ws + off); off += (size_t)n * DIM * 2;
    __bf16* kb = (__bf16*)(ws + off); off += (size_t)m * DIM * 2;
    __bf16* vb = (__bf16*)(ws + off); off += (size_t)m * DIM * 2;
    int* row_ptr = (int*)(ws + off);  off += (size_t)(n + 1) * 4;
    // total ~38.7 MB

    prep_w_kernel<<<dim3(64, 3), 256, 0, stream>>>(Wq, Wk, Wv, Wt);

    row_ptr_kernel<<<dim3((n + 1 + 255) / 256), 256, 0, stream>>>(rows, row_ptr, n, e);

    int max_r = (n > m) ? n : m;
    proj_gemm_kernel<<<dim3((max_r + 127) / 128, 3), 256, 0, stream>>>(
        query, memory, Wt, bq, bk, bv, qb, kb, vb, n, m);

    edge_attn_kernel<<<dim3((n + 3) / 4), 256, 0, stream>>>(
        qb, kb, vb, adj_vals, cols, row_ptr, out, n);
}